// Round 1
// baseline (210.995 us; speedup 1.0000x reference)
//
#include <hip/hip_runtime.h>
#include <math.h>

#define HH 384
#define WW 512
#define RR 60
#define KLEN 121          // 2*RR+1
#define SIG 20.0
#define TH 16             // rows per tile in main kernel
#define NTILES (HH / TH)  // 24

// ---------------- kernel weights + prefix sums (single thread, double prec) ---
__global__ void k_init(float* kk, float* P) {
    if (threadIdx.x == 0 && blockIdx.x == 0) {
        double tmp[KLEN];
        double s = 0.0;
        for (int t = 0; t < KLEN; ++t) {
            double xx = (double)(t - RR) / SIG;
            tmp[t] = exp(-0.5 * xx * xx);
            s += tmp[t];
        }
        double run = 0.0;
        for (int t = 0; t < KLEN; ++t) {
            double v = tmp[t] / s;
            kk[t] = (float)v;
            P[t] = (float)run;
            run += v;
        }
        P[KLEN] = (float)run;
    }
}

// ---------------- histogram of fixations per image ----------------------------
__global__ void k_hist(const int* __restrict__ ns, int* __restrict__ cnt, int nfix) {
    int i = blockIdx.x * blockDim.x + threadIdx.x;
    if (i < nfix) atomicAdd(&cnt[ns[i]], 1);
}

// ---------------- exclusive scan over batch (tiny, 1 thread) ------------------
__global__ void k_scan(const int* __restrict__ cnt, int* __restrict__ offs, int batch) {
    if (threadIdx.x == 0 && blockIdx.x == 0) {
        int run = 0;
        for (int n = 0; n < batch; ++n) { offs[n] = run; run += cnt[n]; }
        offs[batch] = run;
    }
}

// ---------------- scatter fixations into CSR + analytic per-image mass --------
__global__ void k_scatter(const int* __restrict__ ns, const int* __restrict__ ys,
                          const int* __restrict__ xs, const float* __restrict__ P,
                          const int* __restrict__ offs, int* __restrict__ cur,
                          int* __restrict__ sorted, float* __restrict__ ssum, int nfix) {
    int i = blockIdx.x * blockDim.x + threadIdx.x;
    if (i >= nfix) return;
    int n = ns[i], y = ys[i], x = xs[i];
    int pos = atomicAdd(&cur[n], 1);
    sorted[offs[n] + pos] = (y << 9) | x;
    // clipped column/row kernel mass (zero padding in the reference conv)
    float cy = P[RR + min(RR, HH - 1 - y) + 1] - P[RR - min(RR, y)];
    float cx = P[RR + min(RR, WW - 1 - x) + 1] - P[RR - min(RR, x)];
    atomicAdd(&ssum[n], cy * cx);
}

// ---------------- saliency total ----------------------------------------------
__global__ __launch_bounds__(256) void k_salsum(const float* __restrict__ sal,
                                                float* __restrict__ ssal, int n) {
    int i = blockIdx.x * blockDim.x + threadIdx.x;
    float v = (i < n) ? sal[i] : 0.f;
    for (int o = 32; o > 0; o >>= 1) v += __shfl_down(v, o, 64);
    __shared__ float part[4];
    int lane = threadIdx.x & 63, wid = threadIdx.x >> 6;
    if (lane == 0) part[wid] = v;
    __syncthreads();
    if (threadIdx.x == 0) atomicAdd(ssal, part[0] + part[1] + part[2] + part[3]);
}

// ---------------- main: splat Gaussians into LDS tile, fused min-sum ----------
__global__ __launch_bounds__(256) void k_main(const float* __restrict__ sal,
                                              const int* __restrict__ offs,
                                              const int* __restrict__ sorted,
                                              const float* __restrict__ ssum,
                                              const float* __restrict__ ssal,
                                              const float* __restrict__ kk,
                                              float* __restrict__ out) {
    __shared__ float tile[TH][WW];
    __shared__ float kk_s[KLEN];
    __shared__ float part[4];

    const int n = blockIdx.y;
    const int r0 = blockIdx.x * TH;
    const int tid = threadIdx.x;

    for (int p = tid; p < TH * WW; p += 256) ((float*)tile)[p] = 0.f;
    if (tid < KLEN) kk_s[tid] = kk[tid];
    __syncthreads();

    const int s0 = offs[n], s1 = offs[n + 1];
    for (int f = s0; f < s1; ++f) {
        const int packed = sorted[f];          // uniform across block
        const int y = packed >> 9, x = packed & 511;
        if (y >= r0 - RR && y <= r0 + TH - 1 + RR) {   // uniform branch
            const int i0 = max(r0, y - RR), i1 = min(r0 + TH - 1, y + RR);
            const int j0 = max(0, x - RR),  j1 = min(WW - 1, x + RR);
            const int ncols = j1 - j0 + 1;     // <= 121
            const int c = tid & 127;           // col within splat
            const int rb = tid >> 7;           // 0/1 row phase
            if (c < ncols) {
                const float wx = kk_s[c + j0 - x + RR];
                for (int i = i0 + rb; i <= i1; i += 2)
                    tile[i - r0][j0 + c] += kk_s[i - y + RR] * wx;
            }
        }
        __syncthreads();   // fixations write overlapping elements; waves must not skew
    }

    const float sN = ssum[n];
    const float invSn = sN > 0.f ? 1.0f / sN : 0.f;
    const float invSal = 1.0f / ssal[0];
    float acc = 0.f;
    for (int p = tid; p < TH * WW; p += 256) {
        const int i = p >> 9, j = p & 511;
        const float e = tile[i][j] * invSn;
        const float s = sal[(r0 + i) * WW + j] * invSal;
        acc += fminf(e, s);
    }
    for (int o = 32; o > 0; o >>= 1) acc += __shfl_down(acc, o, 64);
    const int lane = tid & 63, wid = tid >> 6;
    if (lane == 0) part[wid] = acc;
    __syncthreads();
    if (tid == 0) atomicAdd(&out[n], part[0] + part[1] + part[2] + part[3]);
}

extern "C" void kernel_launch(void* const* d_in, const int* in_sizes, int n_in,
                              void* d_out, int out_size, void* d_ws, size_t ws_size,
                              hipStream_t stream) {
    const float* sal = (const float*)d_in[0];
    const int* ns = (const int*)d_in[1];
    const int* ys = (const int*)d_in[2];
    const int* xs = (const int*)d_in[3];
    const int nfix = in_sizes[1];
    const int batch = out_size;          // 128; d_in[4] (batch_size) unused on host
    float* out = (float*)d_out;

    // ws layout (float-element offsets); total ~ (320 + 4*batch + 1 + nfix) * 4B  (~55 KB)
    float* ws   = (float*)d_ws;
    float* kk   = ws;              // 121 floats (pad to 128)
    float* P    = ws + 128;        // 122 floats (pad to 128)
    float* ssal = ws + 256;        // 1 float (pad to 64)
    float* ssum = ws + 320;        // batch floats
    int*   cnt  = (int*)(ws + 320 + batch);   // batch ints
    int*   offs = cnt + batch;                // batch+1 ints
    int*   cur  = offs + batch + 1;           // batch ints
    int*   sorted = cur + batch;              // nfix ints

    // zero all accumulators each call (harness does not re-poison between replays)
    size_t zbytes = (char*)(cur + batch) - (char*)ssal;
    hipMemsetAsync(ssal, 0, zbytes, stream);
    hipMemsetAsync(out, 0, (size_t)batch * sizeof(float), stream);

    k_init<<<1, 64, 0, stream>>>(kk, P);
    int fb = (nfix + 255) / 256;
    k_hist<<<fb, 256, 0, stream>>>(ns, cnt, nfix);
    k_scan<<<1, 64, 0, stream>>>(cnt, offs, batch);
    k_scatter<<<fb, 256, 0, stream>>>(ns, ys, xs, P, offs, cur, sorted, ssum, nfix);
    int sb = (HH * WW + 255) / 256;
    k_salsum<<<sb, 256, 0, stream>>>(sal, ssal, HH * WW);
    k_main<<<dim3(NTILES, batch), 256, 0, stream>>>(sal, offs, sorted, ssum, ssal, kk, out);
}

// Round 2
// 81.370 us; speedup vs baseline: 2.5930x; 2.5930x over previous
//
#include <hip/hip_runtime.h>
#include <math.h>

#define HH 384
#define WW 512
#define RR 60
#define KLEN 121          // 2*RR+1
#define TH 16             // rows per tile in k_main
#define NTILES (HH / TH)  // 24
#define MAXB 256          // LDS array bound for batch (actual batch = 128)

// ---------------- fused preamble: weights + hist + scan + scatter + salsum ----
// Single block, 1024 threads. No cross-block deps -> no memsets needed.
__global__ __launch_bounds__(1024) void k_pre(
    const float* __restrict__ sal, const int* __restrict__ ns,
    const int* __restrict__ ys, const int* __restrict__ xs,
    float* __restrict__ kk_g, float* __restrict__ ssal,
    float* __restrict__ ssum_g, int* __restrict__ offs_g,
    int* __restrict__ sorted, float* __restrict__ out,
    int nfix, int batch)
{
    __shared__ int   cnt_s[MAXB];
    __shared__ int   offs_s[MAXB + 1];
    __shared__ int   cur_s[MAXB];
    __shared__ float ssum_s[MAXB];
    __shared__ float kk_s[KLEN];
    __shared__ float P_s[KLEN + 1];
    __shared__ float red[16];

    const int tid = threadIdx.x;

    if (tid < batch) { cnt_s[tid] = 0; cur_s[tid] = 0; ssum_s[tid] = 0.f; out[tid] = 0.f; }
    if (tid < KLEN) {
        float xx = (float)(tid - RR) * (1.0f / 20.0f);
        kk_s[tid] = expf(-0.5f * xx * xx);
    }
    __syncthreads();
    if (tid == 0) {                    // normalize + prefix (121 float ops, trivial)
        float s = 0.f;
        for (int t = 0; t < KLEN; ++t) s += kk_s[t];
        float inv = 1.0f / s, run = 0.f;
        for (int t = 0; t < KLEN; ++t) {
            float v = kk_s[t] * inv;
            kk_s[t] = v; P_s[t] = run; run += v;
        }
        P_s[KLEN] = run;
    }
    __syncthreads();
    // histogram (LDS atomics)
    for (int i = tid; i < nfix; i += 1024) atomicAdd(&cnt_s[ns[i]], 1);
    __syncthreads();
    if (tid == 0) {                    // exclusive scan over batch
        int run = 0;
        for (int b = 0; b < batch; ++b) { offs_s[b] = run; run += cnt_s[b]; }
        offs_s[batch] = run;
    }
    __syncthreads();
    // scatter into CSR + analytic per-image kernel mass (zero-pad clipping)
    for (int i = tid; i < nfix; i += 1024) {
        int n = ns[i], y = ys[i], x = xs[i];
        int pos = atomicAdd(&cur_s[n], 1);
        sorted[offs_s[n] + pos] = (y << 9) | x;
        float cy = P_s[RR + min(RR, HH - 1 - y) + 1] - P_s[RR - min(RR, y)];
        float cx = P_s[RR + min(RR, WW - 1 - x) + 1] - P_s[RR - min(RR, x)];
        atomicAdd(&ssum_s[n], cy * cx);
    }
    // saliency total (float4 grid-stride within the block)
    float a = 0.f;
    const float4* s4 = (const float4*)sal;
    for (int i = tid; i < (HH * WW) / 4; i += 1024) {
        float4 v = s4[i];
        a += (v.x + v.y) + (v.z + v.w);
    }
    for (int o = 32; o > 0; o >>= 1) a += __shfl_down(a, o, 64);
    if ((tid & 63) == 0) red[tid >> 6] = a;
    __syncthreads();                   // also fences scatter-loop LDS atomics
    if (tid == 0) {
        float t = 0.f;
        for (int w = 0; w < 16; ++w) t += red[w];
        ssal[0] = t;
    }
    // export to global for k_main
    if (tid < KLEN) kk_g[tid] = kk_s[tid];
    if (tid < batch) ssum_g[tid] = ssum_s[tid];
    if (tid <= batch) offs_g[tid] = offs_s[tid];
}

// ---------------- main: register-accumulator Gaussian splat, fused min-sum ----
// Thread t owns columns t and t+256 of a 16-row tile => no races, no barriers
// in the splat loop.
__global__ __launch_bounds__(256) void k_main(
    const float* __restrict__ sal, const int* __restrict__ offs,
    const int* __restrict__ sorted, const float* __restrict__ ssum,
    const float* __restrict__ ssal, const float* __restrict__ kk_g,
    float* __restrict__ out)
{
    __shared__ float kpy[160];   // y-kernel padded: [16..136] = kk, rest 0
    __shared__ float kkx[128];   // x-kernel: [0..120] = kk, [121..127] = 0
    __shared__ int   fix_s[256];
    __shared__ float part[4];

    const int n   = blockIdx.y;
    const int r0  = blockIdx.x * TH;
    const int tid = threadIdx.x;

    if (tid < 160) kpy[tid] = ((unsigned)(tid - 16) <= 120u) ? kk_g[tid - 16] : 0.f;
    if (tid < 128) kkx[tid] = (tid < KLEN) ? kk_g[tid] : 0.f;

    float acc0[TH], acc1[TH];
    #pragma unroll
    for (int i = 0; i < TH; ++i) { acc0[i] = 0.f; acc1[i] = 0.f; }

    const int s0 = offs[n], s1 = offs[n + 1];
    const int c0 = tid, c1 = tid + 256;

    for (int fb = s0; fb < s1; fb += 256) {
        const int m = min(256, s1 - fb);
        __syncthreads();
        if (tid < m) fix_s[tid] = sorted[fb + tid];
        __syncthreads();
        for (int f = 0; f < m; ++f) {
            const int packed = fix_s[f];              // broadcast LDS read
            const int y = packed >> 9, x = packed & 511;
            const int base = r0 - y + 76;             // row-weight base in kpy
            if ((unsigned)(base - 1) >= 136u) continue;   // uniform: tile out of y-range
            const float wx0 = kkx[min((unsigned)(c0 - x + RR), 127u)];
            const float wx1 = kkx[min((unsigned)(c1 - x + RR), 127u)];
            if (wx0 == 0.f && wx1 == 0.f) continue;   // whole-wave skip when possible
            #pragma unroll
            for (int i = 0; i < TH; ++i) {
                const float wy = kpy[i + base];       // broadcast LDS read
                acc0[i] = fmaf(wy, wx0, acc0[i]);
                acc1[i] = fmaf(wy, wx1, acc1[i]);
            }
        }
    }

    const float sN    = ssum[n];
    const float invSn = sN > 0.f ? 1.0f / sN : 0.f;
    const float invSal = 1.0f / ssal[0];
    float acc = 0.f;
    #pragma unroll
    for (int i = 0; i < TH; ++i) {
        const float* row = sal + (size_t)(r0 + i) * WW;
        acc += fminf(acc0[i] * invSn, row[c0] * invSal);   // coalesced
        acc += fminf(acc1[i] * invSn, row[c1] * invSal);
    }
    for (int o = 32; o > 0; o >>= 1) acc += __shfl_down(acc, o, 64);
    if ((tid & 63) == 0) part[tid >> 6] = acc;
    __syncthreads();
    if (tid == 0) atomicAdd(&out[n], part[0] + part[1] + part[2] + part[3]);
}

extern "C" void kernel_launch(void* const* d_in, const int* in_sizes, int n_in,
                              void* d_out, int out_size, void* d_ws, size_t ws_size,
                              hipStream_t stream) {
    const float* sal = (const float*)d_in[0];
    const int* ns = (const int*)d_in[1];
    const int* ys = (const int*)d_in[2];
    const int* xs = (const int*)d_in[3];
    const int nfix = in_sizes[1];
    const int batch = out_size;          // 128
    float* out = (float*)d_out;

    // ws layout (float-element offsets)
    float* ws     = (float*)d_ws;
    float* kk_g   = ws;                        // 128
    float* ssal   = ws + 128;                  // 1 (pad to 64)
    float* ssum_g = ws + 192;                  // batch
    int*   offs_g = (int*)(ws + 192 + batch);  // batch+1 (pad to 192)
    int*   sorted = offs_g + 192;              // nfix

    k_pre<<<1, 1024, 0, stream>>>(sal, ns, ys, xs, kk_g, ssal, ssum_g,
                                  offs_g, sorted, out, nfix, batch);
    k_main<<<dim3(NTILES, batch), 256, 0, stream>>>(sal, offs_g, sorted,
                                                    ssum_g, ssal, kk_g, out);
}

// Round 3
// 67.537 us; speedup vs baseline: 3.1241x; 1.2048x over previous
//
#include <hip/hip_runtime.h>
#include <math.h>

#define HH 384
#define WW 512
#define RR 60
#define KLEN 121           // 2*RR+1
#define TH 16              // rows per tile in k_main
#define NTILES (HH / TH)   // 24
#define BATCH 128          // harness batch (out_size); LDS sizing assumes <=128
#define NB (BATCH * NTILES)  // 3072 (image, y-tile) buckets

// ---------------- saliency total: full-chip atomic reduce ---------------------
__global__ __launch_bounds__(256) void k_salsum(const float* __restrict__ sal,
                                                float* __restrict__ ssal) {
    __shared__ float red[4];
    const int i = blockIdx.x * 256 + threadIdx.x;   // grid covers HH*WW/4 exactly
    float4 v = ((const float4*)sal)[i];
    float a = (v.x + v.y) + (v.z + v.w);
    for (int o = 32; o > 0; o >>= 1) a += __shfl_down(a, o, 64);
    if ((threadIdx.x & 63) == 0) red[threadIdx.x >> 6] = a;
    __syncthreads();
    if (threadIdx.x == 0) atomicAdd(ssal, red[0] + red[1] + red[2] + red[3]);
}

// ---------------- preamble: weights + bucket sort + analytic mass -------------
// Single block, 1024 threads. Buckets fixations by (image, y>>4) so k_main
// blocks read only their 9 relevant buckets.
__global__ __launch_bounds__(1024) void k_pre(
    const int* __restrict__ ns, const int* __restrict__ ys,
    const int* __restrict__ xs,
    float* __restrict__ kk_g, float* __restrict__ ssum_g,
    int* __restrict__ offs_g, int* __restrict__ sorted,
    float* __restrict__ out, int nfix, int batch)
{
    __shared__ int   cnt_s[NB];
    __shared__ int   cur_s[NB];
    __shared__ int   offs_s[NB + 1];
    __shared__ int   img_tot[BATCH];
    __shared__ float ssum_s[BATCH];
    __shared__ float kk_s[KLEN];
    __shared__ float P_s[KLEN + 1];

    const int tid = threadIdx.x;

    for (int i = tid; i < NB; i += 1024) { cnt_s[i] = 0; cur_s[i] = 0; }
    if (tid < BATCH) { ssum_s[tid] = 0.f; out[tid] = 0.f; }
    if (tid < KLEN) {
        float xx = (float)(tid - RR) * (1.0f / 20.0f);
        kk_s[tid] = expf(-0.5f * xx * xx);
    }
    __syncthreads();
    if (tid == 0) {                    // normalize + prefix (242 float ops)
        float s = 0.f;
        for (int t = 0; t < KLEN; ++t) s += kk_s[t];
        float inv = 1.0f / s, run = 0.f;
        for (int t = 0; t < KLEN; ++t) {
            float v = kk_s[t] * inv;
            kk_s[t] = v; P_s[t] = run; run += v;
        }
        P_s[KLEN] = run;
    }
    __syncthreads();
    // bucket histogram
    for (int i = tid; i < nfix; i += 1024)
        atomicAdd(&cnt_s[ns[i] * NTILES + (ys[i] >> 4)], 1);
    __syncthreads();
    // hierarchical exclusive scan: per-image serial (128 threads x 24), then image level
    if (tid < BATCH) {
        int run = 0;
        for (int t = 0; t < NTILES; ++t) {
            int c = cnt_s[tid * NTILES + t];
            cnt_s[tid * NTILES + t] = run;
            run += c;
        }
        img_tot[tid] = run;
    }
    __syncthreads();
    if (tid == 0) {
        int run = 0;
        for (int b = 0; b < BATCH; ++b) { int c = img_tot[b]; img_tot[b] = run; run += c; }
    }
    __syncthreads();
    for (int i = tid; i < NB; i += 1024) offs_s[i] = cnt_s[i] + img_tot[i / NTILES];
    if (tid == 0) offs_s[NB] = nfix;
    __syncthreads();
    // scatter into bucket-CSR + analytic per-image kernel mass (zero-pad clipping)
    for (int i = tid; i < nfix; i += 1024) {
        int n = ns[i], y = ys[i], x = xs[i];
        int key = n * NTILES + (y >> 4);
        int pos = atomicAdd(&cur_s[key], 1);
        sorted[offs_s[key] + pos] = (y << 9) | x;
        float cy = P_s[RR + min(RR, HH - 1 - y) + 1] - P_s[RR - min(RR, y)];
        float cx = P_s[RR + min(RR, WW - 1 - x) + 1] - P_s[RR - min(RR, x)];
        atomicAdd(&ssum_s[n], cy * cx);
    }
    __syncthreads();
    // export
    for (int i = tid; i <= NB; i += 1024) offs_g[i] = offs_s[i];
    if (tid < KLEN) kk_g[tid] = kk_s[tid];
    if (tid < BATCH) ssum_g[tid] = ssum_s[tid];
}

// ---------------- main: register-accumulator Gaussian splat, fused min-sum ----
// Thread t owns adjacent columns 2t,2t+1 => wave w owns a contiguous 128-col
// strip => wave-uniform x-range skip. Bucket CSR removes the y-filter scan.
__global__ __launch_bounds__(256) void k_main(
    const float* __restrict__ sal, const int* __restrict__ offs,
    const int* __restrict__ sorted, const float* __restrict__ ssum,
    const float* __restrict__ ssal, const float* __restrict__ kk_g,
    float* __restrict__ out)
{
    __shared__ float kpy[160];   // y-kernel padded: [16..136] = kk, rest 0
    __shared__ float kkx[128];   // x-kernel: [0..120] = kk, [121..127] = 0
    __shared__ int   fix_s[256];
    __shared__ float part[4];

    const int n   = blockIdx.y;
    const int t   = blockIdx.x;
    const int r0  = t * TH;
    const int tid = threadIdx.x;

    if (tid < 160) kpy[tid] = ((unsigned)(tid - 16) <= 120u) ? kk_g[tid - 16] : 0.f;
    if (tid < 128) kkx[tid] = (tid < KLEN) ? kk_g[tid] : 0.f;

    float acc0[TH], acc1[TH];
    #pragma unroll
    for (int i = 0; i < TH; ++i) { acc0[i] = 0.f; acc1[i] = 0.f; }

    const int b0 = n * NTILES + max(0, t - 4);
    const int b1 = n * NTILES + min(NTILES - 1, t + 4);
    const int s0 = offs[b0], s1 = offs[b1 + 1];

    const int c0  = 2 * tid;
    const int wlo = (tid >> 6) << 7;      // wave's column strip [wlo, wlo+127]
    const int whi = wlo + 127;

    for (int fb = s0; fb < s1; fb += 256) {
        const int m = min(256, s1 - fb);
        __syncthreads();
        if (tid < m) fix_s[tid] = sorted[fb + tid];
        __syncthreads();
        for (int f = 0; f < m; ++f) {
            const int packed = fix_s[f];              // broadcast LDS read
            const int y = packed >> 9, x = packed & 511;
            const int base = r0 - y + 76;             // row-weight base in kpy
            if ((unsigned)(base - 1) >= 136u) continue;   // uniform: y out of range
            if (x + RR < wlo || x - RR > whi) continue;   // uniform per wave: x skip
            const int idx0 = c0 - x + RR;
            const float wx0 = kkx[min((unsigned)idx0, 127u)];
            const float wx1 = kkx[min((unsigned)(idx0 + 1), 127u)];
            #pragma unroll
            for (int i = 0; i < TH; ++i) {
                const float wy = kpy[i + base];       // broadcast LDS read
                acc0[i] = fmaf(wy, wx0, acc0[i]);
                acc1[i] = fmaf(wy, wx1, acc1[i]);
            }
        }
    }

    const float sN     = ssum[n];
    const float invSn  = sN > 0.f ? 1.0f / sN : 0.f;
    const float invSal = 1.0f / ssal[0];
    float acc = 0.f;
    #pragma unroll
    for (int i = 0; i < TH; ++i) {
        const float2 v = ((const float2*)(sal + (size_t)(r0 + i) * WW))[tid];
        acc += fminf(acc0[i] * invSn, v.x * invSal);
        acc += fminf(acc1[i] * invSn, v.y * invSal);
    }
    for (int o = 32; o > 0; o >>= 1) acc += __shfl_down(acc, o, 64);
    if ((tid & 63) == 0) part[tid >> 6] = acc;
    __syncthreads();
    if (tid == 0) atomicAdd(&out[n], part[0] + part[1] + part[2] + part[3]);
}

extern "C" void kernel_launch(void* const* d_in, const int* in_sizes, int n_in,
                              void* d_out, int out_size, void* d_ws, size_t ws_size,
                              hipStream_t stream) {
    const float* sal = (const float*)d_in[0];
    const int* ns = (const int*)d_in[1];
    const int* ys = (const int*)d_in[2];
    const int* xs = (const int*)d_in[3];
    const int nfix = in_sizes[1];
    const int batch = out_size;          // 128
    float* out = (float*)d_out;

    // ws layout (float-element offsets)
    float* ws     = (float*)d_ws;
    float* kk_g   = ws;                        // 128
    float* ssal   = ws + 128;                  // 1 (pad to 64)
    float* ssum_g = ws + 192;                  // BATCH
    int*   offs_g = (int*)(ws + 192 + BATCH);  // NB+1 ints (3073)
    int*   sorted = offs_g + NB + 1;           // nfix ints

    hipMemsetAsync(ssal, 0, sizeof(float), stream);

    k_salsum<<<(HH * WW / 4) / 256, 256, 0, stream>>>(sal, ssal);
    k_pre<<<1, 1024, 0, stream>>>(ns, ys, xs, kk_g, ssum_g, offs_g, sorted,
                                  out, nfix, batch);
    k_main<<<dim3(NTILES, batch), 256, 0, stream>>>(sal, offs_g, sorted,
                                                    ssum_g, ssal, kk_g, out);
}

// Round 4
// 63.282 us; speedup vs baseline: 3.3342x; 1.0672x over previous
//
#include <hip/hip_runtime.h>
#include <math.h>

#define HH 384
#define WW 512
#define RR 60
#define KLEN 121           // 2*RR+1
#define TH 16              // rows per tile in k_main
#define NTILES (HH / TH)   // 24
#define BATCH 128          // harness batch (out_size); LDS sizing assumes <=128
#define NB (BATCH * NTILES)  // 3072 (image, y-tile) buckets
#define SBLK 192           // k_salsum blocks = HH*WW/4/256

// ---------------- saliency partial sums: one plain store per block ------------
__global__ __launch_bounds__(256) void k_salsum(const float* __restrict__ sal,
                                                float* __restrict__ partial) {
    __shared__ float red[4];
    const int i = blockIdx.x * 256 + threadIdx.x;   // grid covers HH*WW/4 exactly
    float4 v = ((const float4*)sal)[i];
    float a = (v.x + v.y) + (v.z + v.w);
    for (int o = 32; o > 0; o >>= 1) a += __shfl_down(a, o, 64);
    if ((threadIdx.x & 63) == 0) red[threadIdx.x >> 6] = a;
    __syncthreads();
    if (threadIdx.x == 0) partial[blockIdx.x] = red[0] + red[1] + red[2] + red[3];
}

// ---------------- preamble: weights + bucket sort + mass + ssal reduce --------
// Single block, 1024 threads. Buckets fixations by (image, y>>4) so k_main
// blocks read only their 9 relevant buckets. Also reduces k_salsum partials.
__global__ __launch_bounds__(1024) void k_pre(
    const int* __restrict__ ns, const int* __restrict__ ys,
    const int* __restrict__ xs, const float* __restrict__ partial,
    float* __restrict__ kk_g, float* __restrict__ ssal,
    float* __restrict__ ssum_g, int* __restrict__ offs_g,
    int* __restrict__ sorted, float* __restrict__ out,
    int nfix, int batch)
{
    __shared__ int   cnt_s[NB];
    __shared__ int   cur_s[NB];
    __shared__ int   offs_s[NB + 1];
    __shared__ int   img_tot[BATCH];
    __shared__ float ssum_s[BATCH];
    __shared__ float kk_s[KLEN];
    __shared__ float P_s[KLEN + 1];
    __shared__ float red[16];

    const int tid = threadIdx.x;

    for (int i = tid; i < NB; i += 1024) { cnt_s[i] = 0; cur_s[i] = 0; }
    if (tid < BATCH) { ssum_s[tid] = 0.f; out[tid] = 0.f; }
    if (tid < KLEN) {
        float xx = (float)(tid - RR) * (1.0f / 20.0f);
        kk_s[tid] = expf(-0.5f * xx * xx);
    }
    // reduce saliency partials (192 floats) in parallel with setup
    {
        float a = (tid < SBLK) ? partial[tid] : 0.f;
        for (int o = 32; o > 0; o >>= 1) a += __shfl_down(a, o, 64);
        if ((tid & 63) == 0) red[tid >> 6] = a;
    }
    __syncthreads();
    if (tid == 0) {                    // normalize + prefix (242 float ops)
        float s = 0.f;
        for (int t = 0; t < KLEN; ++t) s += kk_s[t];
        float inv = 1.0f / s, run = 0.f;
        for (int t = 0; t < KLEN; ++t) {
            float v = kk_s[t] * inv;
            kk_s[t] = v; P_s[t] = run; run += v;
        }
        P_s[KLEN] = run;
    }
    if (tid == 64) {                   // ssal total (waves independent)
        float t = 0.f;
        for (int w = 0; w < 16; ++w) t += red[w];
        ssal[0] = t;
    }
    __syncthreads();
    // bucket histogram (int4 loads)
    const int4* ns4 = (const int4*)ns;
    const int4* ys4 = (const int4*)ys;
    const int4* xs4 = (const int4*)xs;
    const int nf4 = nfix >> 2;
    for (int i = tid; i < nf4; i += 1024) {
        int4 n4 = ns4[i], y4 = ys4[i];
        atomicAdd(&cnt_s[n4.x * NTILES + (y4.x >> 4)], 1);
        atomicAdd(&cnt_s[n4.y * NTILES + (y4.y >> 4)], 1);
        atomicAdd(&cnt_s[n4.z * NTILES + (y4.z >> 4)], 1);
        atomicAdd(&cnt_s[n4.w * NTILES + (y4.w >> 4)], 1);
    }
    for (int i = (nf4 << 2) + tid; i < nfix; i += 1024)
        atomicAdd(&cnt_s[ns[i] * NTILES + (ys[i] >> 4)], 1);
    __syncthreads();
    // hierarchical exclusive scan: per-image serial, then image level
    if (tid < BATCH) {
        int run = 0;
        for (int t = 0; t < NTILES; ++t) {
            int c = cnt_s[tid * NTILES + t];
            cnt_s[tid * NTILES + t] = run;
            run += c;
        }
        img_tot[tid] = run;
    }
    __syncthreads();
    if (tid == 0) {
        int run = 0;
        for (int b = 0; b < BATCH; ++b) { int c = img_tot[b]; img_tot[b] = run; run += c; }
    }
    __syncthreads();
    for (int i = tid; i < NB; i += 1024) offs_s[i] = cnt_s[i] + img_tot[i / NTILES];
    if (tid == 0) offs_s[NB] = nfix;
    __syncthreads();
    // scatter into bucket-CSR + analytic per-image kernel mass (zero-pad clipping)
    for (int i = tid; i < nf4; i += 1024) {
        int4 n4 = ns4[i], y4 = ys4[i], x4 = xs4[i];
        #pragma unroll
        for (int e = 0; e < 4; ++e) {
            int n = (&n4.x)[e], y = (&y4.x)[e], x = (&x4.x)[e];
            int key = n * NTILES + (y >> 4);
            int pos = atomicAdd(&cur_s[key], 1);
            sorted[offs_s[key] + pos] = (y << 9) | x;
            float cy = P_s[RR + min(RR, HH - 1 - y) + 1] - P_s[RR - min(RR, y)];
            float cx = P_s[RR + min(RR, WW - 1 - x) + 1] - P_s[RR - min(RR, x)];
            atomicAdd(&ssum_s[n], cy * cx);
        }
    }
    for (int i = (nf4 << 2) + tid; i < nfix; i += 1024) {
        int n = ns[i], y = ys[i], x = xs[i];
        int key = n * NTILES + (y >> 4);
        int pos = atomicAdd(&cur_s[key], 1);
        sorted[offs_s[key] + pos] = (y << 9) | x;
        float cy = P_s[RR + min(RR, HH - 1 - y) + 1] - P_s[RR - min(RR, y)];
        float cx = P_s[RR + min(RR, WW - 1 - x) + 1] - P_s[RR - min(RR, x)];
        atomicAdd(&ssum_s[n], cy * cx);
    }
    __syncthreads();
    // export
    for (int i = tid; i <= NB; i += 1024) offs_g[i] = offs_s[i];
    if (tid < KLEN) kk_g[tid] = kk_s[tid];
    if (tid < BATCH) ssum_g[tid] = ssum_s[tid];
}

// ---------------- main: register-accumulator Gaussian splat, fused min-sum ----
// Thread t owns adjacent columns 2t,2t+1 => wave w owns a contiguous 128-col
// strip => wave-uniform x-range skip. Bucket CSR removes the y-filter scan.
__global__ __launch_bounds__(256) void k_main(
    const float* __restrict__ sal, const int* __restrict__ offs,
    const int* __restrict__ sorted, const float* __restrict__ ssum,
    const float* __restrict__ ssal, const float* __restrict__ kk_g,
    float* __restrict__ out)
{
    __shared__ float kpy[160];   // y-kernel padded: [16..136] = kk, rest 0
    __shared__ float kkx[128];   // x-kernel: [0..120] = kk, [121..127] = 0
    __shared__ int   fix_s[256];
    __shared__ float part[4];

    const int n   = blockIdx.y;
    const int t   = blockIdx.x;
    const int r0  = t * TH;
    const int tid = threadIdx.x;

    if (tid < 160) kpy[tid] = ((unsigned)(tid - 16) <= 120u) ? kk_g[tid - 16] : 0.f;
    if (tid < 128) kkx[tid] = (tid < KLEN) ? kk_g[tid] : 0.f;

    float acc0[TH], acc1[TH];
    #pragma unroll
    for (int i = 0; i < TH; ++i) { acc0[i] = 0.f; acc1[i] = 0.f; }

    const int b0 = n * NTILES + max(0, t - 4);
    const int b1 = n * NTILES + min(NTILES - 1, t + 4);
    const int s0 = offs[b0], s1 = offs[b1 + 1];

    const int c0  = 2 * tid;
    const int wlo = (tid >> 6) << 7;      // wave's column strip [wlo, wlo+127]
    const int whi = wlo + 127;

    for (int fb = s0; fb < s1; fb += 256) {
        const int m = min(256, s1 - fb);
        __syncthreads();
        if (tid < m) fix_s[tid] = sorted[fb + tid];
        __syncthreads();
        for (int f = 0; f < m; ++f) {
            const int packed = fix_s[f];              // broadcast LDS read
            const int y = packed >> 9, x = packed & 511;
            const int base = r0 - y + 76;             // row-weight base in kpy
            if ((unsigned)(base - 1) >= 136u) continue;   // uniform: y out of range
            if (x + RR < wlo || x - RR > whi) continue;   // uniform per wave: x skip
            const int idx0 = c0 - x + RR;
            const float wx0 = kkx[min((unsigned)idx0, 127u)];
            const float wx1 = kkx[min((unsigned)(idx0 + 1), 127u)];
            #pragma unroll
            for (int i = 0; i < TH; ++i) {
                const float wy = kpy[i + base];       // broadcast LDS read
                acc0[i] = fmaf(wy, wx0, acc0[i]);
                acc1[i] = fmaf(wy, wx1, acc1[i]);
            }
        }
    }

    const float sN     = ssum[n];
    const float invSn  = sN > 0.f ? 1.0f / sN : 0.f;
    const float invSal = 1.0f / ssal[0];
    float acc = 0.f;
    #pragma unroll
    for (int i = 0; i < TH; ++i) {
        const float2 v = ((const float2*)(sal + (size_t)(r0 + i) * WW))[tid];
        acc += fminf(acc0[i] * invSn, v.x * invSal);
        acc += fminf(acc1[i] * invSn, v.y * invSal);
    }
    for (int o = 32; o > 0; o >>= 1) acc += __shfl_down(acc, o, 64);
    if ((tid & 63) == 0) part[tid >> 6] = acc;
    __syncthreads();
    if (tid == 0) atomicAdd(&out[n], part[0] + part[1] + part[2] + part[3]);
}

extern "C" void kernel_launch(void* const* d_in, const int* in_sizes, int n_in,
                              void* d_out, int out_size, void* d_ws, size_t ws_size,
                              hipStream_t stream) {
    const float* sal = (const float*)d_in[0];
    const int* ns = (const int*)d_in[1];
    const int* ys = (const int*)d_in[2];
    const int* xs = (const int*)d_in[3];
    const int nfix = in_sizes[1];
    const int batch = out_size;          // 128
    float* out = (float*)d_out;

    // ws layout (float-element offsets)
    float* ws      = (float*)d_ws;
    float* kk_g    = ws;                        // 128
    float* ssal    = ws + 128;                  // 1 (pad to 64)
    float* partial = ws + 192;                  // SBLK floats (pad to 256)
    float* ssum_g  = ws + 448;                  // BATCH
    int*   offs_g  = (int*)(ws + 448 + BATCH);  // NB+1 ints (3073)
    int*   sorted  = offs_g + NB + 1;           // nfix ints

    k_salsum<<<SBLK, 256, 0, stream>>>(sal, partial);
    k_pre<<<1, 1024, 0, stream>>>(ns, ys, xs, partial, kk_g, ssal, ssum_g,
                                  offs_g, sorted, out, nfix, batch);
    k_main<<<dim3(NTILES, batch), 256, 0, stream>>>(sal, offs_g, sorted,
                                                    ssum_g, ssal, kk_g, out);
}

// Round 5
// 59.674 us; speedup vs baseline: 3.5358x; 1.0605x over previous
//
#include <hip/hip_runtime.h>
#include <math.h>

#define HH 384
#define WW 512
#define RR 60
#define KLEN 121             // 2*RR+1
#define TH 16                // rows per tile in k_main
#define NTILES (HH / TH)     // 24
#define BATCH 128            // harness batch (out_size); LDS sizing assumes <=128
#define NB (BATCH * NTILES)  // 3072 (image, y-tile) buckets
#define SBLK 48              // saliency partial blocks: 48*1024 float4 = HH*WW/4

// ---- kernel 1: block 0 = bucket-sort preamble; blocks 1..48 = sal partials --
__global__ __launch_bounds__(1024) void k_prep(
    const float* __restrict__ sal, const int* __restrict__ ns,
    const int* __restrict__ ys, const int* __restrict__ xs,
    float* __restrict__ kk_g, float* __restrict__ partial,
    float* __restrict__ ssum_g, int* __restrict__ offs_g,
    int* __restrict__ sorted, float* __restrict__ out, int nfix)
{
    __shared__ int   cnt_s[NB];
    __shared__ int   cur_s[NB];
    __shared__ int   offs_s[NB + 1];
    __shared__ int   img_tot[BATCH];
    __shared__ float ssum_s[BATCH];
    __shared__ float kk_s[KLEN];
    __shared__ float P_s[KLEN + 1];
    __shared__ float red[16];

    const int tid = threadIdx.x;

    if (blockIdx.x > 0) {
        // ---- saliency partial sum: one float4 per thread, one store per block
        float4 v = ((const float4*)sal)[(blockIdx.x - 1) * 1024 + tid];
        float a = (v.x + v.y) + (v.z + v.w);
        for (int o = 32; o > 0; o >>= 1) a += __shfl_down(a, o, 64);
        if ((tid & 63) == 0) red[tid >> 6] = a;
        __syncthreads();
        if (tid == 0) {
            float t = 0.f;
            for (int w = 0; w < 16; ++w) t += red[w];
            partial[blockIdx.x - 1] = t;
        }
        return;
    }

    // ---- block 0: weights + bucket sort + analytic mass ----
    for (int i = tid; i < NB; i += 1024) { cnt_s[i] = 0; cur_s[i] = 0; }
    if (tid < BATCH) { ssum_s[tid] = 0.f; out[tid] = 0.f; }
    if (tid < KLEN) {
        float xx = (float)(tid - RR) * (1.0f / 20.0f);
        kk_s[tid] = expf(-0.5f * xx * xx);
    }
    __syncthreads();
    if (tid == 0) {                    // normalize + prefix (242 float ops)
        float s = 0.f;
        for (int t = 0; t < KLEN; ++t) s += kk_s[t];
        float inv = 1.0f / s, run = 0.f;
        for (int t = 0; t < KLEN; ++t) {
            float v = kk_s[t] * inv;
            kk_s[t] = v; P_s[t] = run; run += v;
        }
        P_s[KLEN] = run;
    }
    __syncthreads();
    // bucket histogram (int4 loads)
    const int4* ns4 = (const int4*)ns;
    const int4* ys4 = (const int4*)ys;
    const int4* xs4 = (const int4*)xs;
    const int nf4 = nfix >> 2;
    for (int i = tid; i < nf4; i += 1024) {
        int4 n4 = ns4[i], y4 = ys4[i];
        atomicAdd(&cnt_s[n4.x * NTILES + (y4.x >> 4)], 1);
        atomicAdd(&cnt_s[n4.y * NTILES + (y4.y >> 4)], 1);
        atomicAdd(&cnt_s[n4.z * NTILES + (y4.z >> 4)], 1);
        atomicAdd(&cnt_s[n4.w * NTILES + (y4.w >> 4)], 1);
    }
    for (int i = (nf4 << 2) + tid; i < nfix; i += 1024)
        atomicAdd(&cnt_s[ns[i] * NTILES + (ys[i] >> 4)], 1);
    __syncthreads();
    // hierarchical exclusive scan: per-image serial, then image level
    if (tid < BATCH) {
        int run = 0;
        for (int t = 0; t < NTILES; ++t) {
            int c = cnt_s[tid * NTILES + t];
            cnt_s[tid * NTILES + t] = run;
            run += c;
        }
        img_tot[tid] = run;
    }
    __syncthreads();
    if (tid == 0) {
        int run = 0;
        for (int b = 0; b < BATCH; ++b) { int c = img_tot[b]; img_tot[b] = run; run += c; }
    }
    __syncthreads();
    for (int i = tid; i < NB; i += 1024) offs_s[i] = cnt_s[i] + img_tot[i / NTILES];
    if (tid == 0) offs_s[NB] = nfix;
    __syncthreads();
    // scatter into bucket-CSR + analytic per-image kernel mass (zero-pad clipping)
    for (int i = tid; i < nf4; i += 1024) {
        int4 n4 = ns4[i], y4 = ys4[i], x4 = xs4[i];
        #pragma unroll
        for (int e = 0; e < 4; ++e) {
            int n = (&n4.x)[e], y = (&y4.x)[e], x = (&x4.x)[e];
            int key = n * NTILES + (y >> 4);
            int pos = atomicAdd(&cur_s[key], 1);
            sorted[offs_s[key] + pos] = (y << 9) | x;
            float cy = P_s[RR + min(RR, HH - 1 - y) + 1] - P_s[RR - min(RR, y)];
            float cx = P_s[RR + min(RR, WW - 1 - x) + 1] - P_s[RR - min(RR, x)];
            atomicAdd(&ssum_s[n], cy * cx);
        }
    }
    for (int i = (nf4 << 2) + tid; i < nfix; i += 1024) {
        int n = ns[i], y = ys[i], x = xs[i];
        int key = n * NTILES + (y >> 4);
        int pos = atomicAdd(&cur_s[key], 1);
        sorted[offs_s[key] + pos] = (y << 9) | x;
        float cy = P_s[RR + min(RR, HH - 1 - y) + 1] - P_s[RR - min(RR, y)];
        float cx = P_s[RR + min(RR, WW - 1 - x) + 1] - P_s[RR - min(RR, x)];
        atomicAdd(&ssum_s[n], cy * cx);
    }
    __syncthreads();
    // export
    for (int i = tid; i <= NB; i += 1024) offs_g[i] = offs_s[i];
    if (tid < KLEN) kk_g[tid] = kk_s[tid];
    if (tid < BATCH) ssum_g[tid] = ssum_s[tid];
}

// ---------------- main: register-accumulator Gaussian splat, fused min-sum ----
// Thread t owns adjacent columns 2t,2t+1 => wave w owns a contiguous 128-col
// strip => wave-uniform x-range skip. Bucket CSR removes the y-filter scan.
// Also reduces the 48 saliency partials (loads issued before the splat loop).
__global__ __launch_bounds__(256) void k_main(
    const float* __restrict__ sal, const int* __restrict__ offs,
    const int* __restrict__ sorted, const float* __restrict__ ssum,
    const float* __restrict__ partial, const float* __restrict__ kk_g,
    float* __restrict__ out)
{
    __shared__ float kpy[160];   // y-kernel padded: [16..136] = kk, rest 0
    __shared__ float kkx[128];   // x-kernel: [0..120] = kk, [121..127] = 0
    __shared__ int   fix_s[256];
    __shared__ float part[4];
    __shared__ float red[4];

    const int n   = blockIdx.y;
    const int t   = blockIdx.x;
    const int r0  = t * TH;
    const int tid = threadIdx.x;

    if (tid < 160) kpy[tid] = ((unsigned)(tid - 16) <= 120u) ? kk_g[tid - 16] : 0.f;
    if (tid < 128) kkx[tid] = (tid < KLEN) ? kk_g[tid] : 0.f;
    float psal = (tid < SBLK) ? partial[tid] : 0.f;   // issue early; used in epilogue

    float acc0[TH], acc1[TH];
    #pragma unroll
    for (int i = 0; i < TH; ++i) { acc0[i] = 0.f; acc1[i] = 0.f; }

    const int b0 = n * NTILES + max(0, t - 4);
    const int b1 = n * NTILES + min(NTILES - 1, t + 4);
    const int s0 = offs[b0], s1 = offs[b1 + 1];

    const int c0  = 2 * tid;
    const int wlo = (tid >> 6) << 7;      // wave's column strip [wlo, wlo+127]
    const int whi = wlo + 127;

    for (int fb = s0; fb < s1; fb += 256) {
        const int m = min(256, s1 - fb);
        if (fb != s0) __syncthreads();            // protect fix_s overwrite
        if (tid < m) fix_s[tid] = sorted[fb + tid];
        __syncthreads();                          // also covers kpy/kkx first time
        for (int f = 0; f < m; ++f) {
            const int packed = fix_s[f];              // broadcast LDS read
            const int y = packed >> 9, x = packed & 511;
            const int base = r0 - y + 76;             // row-weight base in kpy
            if ((unsigned)(base - 1) >= 136u) continue;   // uniform: y out of range
            if (x + RR < wlo || x - RR > whi) continue;   // uniform per wave: x skip
            const int idx0 = c0 - x + RR;
            const float wx0 = kkx[min((unsigned)idx0, 127u)];
            const float wx1 = kkx[min((unsigned)(idx0 + 1), 127u)];
            #pragma unroll
            for (int i = 0; i < TH; ++i) {
                const float wy = kpy[i + base];       // broadcast LDS read
                acc0[i] = fmaf(wy, wx0, acc0[i]);
                acc1[i] = fmaf(wy, wx1, acc1[i]);
            }
        }
    }

    // reduce saliency partials -> invSal
    for (int o = 32; o > 0; o >>= 1) psal += __shfl_down(psal, o, 64);
    if ((tid & 63) == 0) red[tid >> 6] = psal;
    __syncthreads();
    const float invSal = 1.0f / (red[0] + red[1] + red[2] + red[3]);

    const float sN    = ssum[n];
    const float invSn = sN > 0.f ? 1.0f / sN : 0.f;
    float acc = 0.f;
    #pragma unroll
    for (int i = 0; i < TH; ++i) {
        const float2 v = ((const float2*)(sal + (size_t)(r0 + i) * WW))[tid];
        acc += fminf(acc0[i] * invSn, v.x * invSal);
        acc += fminf(acc1[i] * invSn, v.y * invSal);
    }
    for (int o = 32; o > 0; o >>= 1) acc += __shfl_down(acc, o, 64);
    if ((tid & 63) == 0) part[tid >> 6] = acc;
    __syncthreads();
    if (tid == 0) atomicAdd(&out[n], part[0] + part[1] + part[2] + part[3]);
}

extern "C" void kernel_launch(void* const* d_in, const int* in_sizes, int n_in,
                              void* d_out, int out_size, void* d_ws, size_t ws_size,
                              hipStream_t stream) {
    const float* sal = (const float*)d_in[0];
    const int* ns = (const int*)d_in[1];
    const int* ys = (const int*)d_in[2];
    const int* xs = (const int*)d_in[3];
    const int nfix = in_sizes[1];
    const int batch = out_size;          // 128
    float* out = (float*)d_out;

    // ws layout (float-element offsets)
    float* ws      = (float*)d_ws;
    float* kk_g    = ws;                        // 128
    float* partial = ws + 128;                  // SBLK floats (pad to 64)
    float* ssum_g  = ws + 192;                  // BATCH
    int*   offs_g  = (int*)(ws + 192 + BATCH);  // NB+1 ints (3073)
    int*   sorted  = offs_g + NB + 1;           // nfix ints

    k_prep<<<SBLK + 1, 1024, 0, stream>>>(sal, ns, ys, xs, kk_g, partial,
                                          ssum_g, offs_g, sorted, out, nfix);
    k_main<<<dim3(NTILES, batch), 256, 0, stream>>>(sal, offs_g, sorted,
                                                    ssum_g, partial, kk_g, out);
}

// Round 6
// 47.001 us; speedup vs baseline: 4.4891x; 1.2696x over previous
//
#include <hip/hip_runtime.h>
#include <math.h>

#define HH 384
#define WW 512
#define RR 60
#define KLEN 121             // 2*RR+1
#define TH 16                // rows per tile in k_main
#define NTILES (HH / TH)     // 24
#define BATCH 128            // harness batch (out_size)
#define MAXF 400             // per-image fixation capacity (mean ~100)
#define SALB 192             // saliency partial blocks: 192*256 float4 = HH*WW

typedef float v2f __attribute__((ext_vector_type(2)));

// ---- kernel 1: blocks [0,batch) = per-image bucket sort + mass;
//                blocks [batch, batch+SALB) = saliency partial sums ----------
__global__ __launch_bounds__(256) void k_prep(
    const float* __restrict__ sal, const int* __restrict__ ns,
    const int* __restrict__ ys, const int* __restrict__ xs,
    float* __restrict__ kk_g, float* __restrict__ partial,
    float* __restrict__ ssum_g, int* __restrict__ offs_g,
    int* __restrict__ sorted, float* __restrict__ out,
    int nfix, int batch)
{
    const int tid = threadIdx.x;

    if (blockIdx.x >= batch) {
        // ---- saliency partial: 256 float4 per block, one plain store -------
        __shared__ float redp[4];
        const int sb = blockIdx.x - batch;
        float4 v = ((const float4*)sal)[sb * 256 + tid];
        float a = (v.x + v.y) + (v.z + v.w);
        for (int o = 32; o > 0; o >>= 1) a += __shfl_down(a, o, 64);
        if ((tid & 63) == 0) redp[tid >> 6] = a;
        __syncthreads();
        if (tid == 0) partial[sb] = redp[0] + redp[1] + redp[2] + redp[3];
        return;
    }

    // ---- per-image block ----
    __shared__ float kk_s[KLEN];
    __shared__ float P_s[KLEN + 1];
    __shared__ int   list[MAXF];
    __shared__ int   cntb[NTILES];
    __shared__ int   off_s[NTILES + 1];
    __shared__ int   cur[NTILES];
    __shared__ int   nloc;
    __shared__ float red2[4];

    const int n = blockIdx.x;

    if (tid < KLEN) {
        float xx = (float)(tid - RR) * (1.0f / 20.0f);
        kk_s[tid] = expf(-0.5f * xx * xx);
    }
    if (tid < NTILES) { cntb[tid] = 0; cur[tid] = 0; }
    if (tid == 0) nloc = 0;
    __syncthreads();
    if (tid == 0) {                    // normalize + prefix (242 float ops)
        float s = 0.f;
        for (int t = 0; t < KLEN; ++t) s += kk_s[t];
        float inv = 1.0f / s, run = 0.f;
        for (int t = 0; t < KLEN; ++t) {
            float v = kk_s[t] * inv;
            kk_s[t] = v; P_s[t] = run; run += v;
        }
        P_s[KLEN] = run;
    }
    __syncthreads();

    // scan all fixations (ns is L2-resident), collect this image's
    float ss = 0.f;
    const int4* ns4 = (const int4*)ns;
    const int nf4 = nfix >> 2;
    for (int i = tid; i < nf4; i += 256) {
        int4 n4 = ns4[i];
        #pragma unroll
        for (int e = 0; e < 4; ++e) {
            if ((&n4.x)[e] == n) {
                const int idx = 4 * i + e;
                const int y = ys[idx], x = xs[idx];
                const int pos = atomicAdd(&nloc, 1);
                if (pos < MAXF) list[pos] = (y << 9) | x;
                atomicAdd(&cntb[y >> 4], 1);
                float cy = P_s[RR + min(RR, HH - 1 - y) + 1] - P_s[RR - min(RR, y)];
                float cx = P_s[RR + min(RR, WW - 1 - x) + 1] - P_s[RR - min(RR, x)];
                ss += cy * cx;
            }
        }
    }
    for (int idx = (nf4 << 2) + tid; idx < nfix; idx += 256) {
        if (ns[idx] == n) {
            const int y = ys[idx], x = xs[idx];
            const int pos = atomicAdd(&nloc, 1);
            if (pos < MAXF) list[pos] = (y << 9) | x;
            atomicAdd(&cntb[y >> 4], 1);
            float cy = P_s[RR + min(RR, HH - 1 - y) + 1] - P_s[RR - min(RR, y)];
            float cx = P_s[RR + min(RR, WW - 1 - x) + 1] - P_s[RR - min(RR, x)];
            ss += cy * cx;
        }
    }
    for (int o = 32; o > 0; o >>= 1) ss += __shfl_down(ss, o, 64);
    if ((tid & 63) == 0) red2[tid >> 6] = ss;
    __syncthreads();                   // atomics + red2 done
    if (tid == 0) {
        ssum_g[n] = red2[0] + red2[1] + red2[2] + red2[3];
        int run = 0;                   // exclusive scan over 24 buckets
        for (int t = 0; t < NTILES; ++t) { off_s[t] = run; run += cntb[t]; }
        off_s[NTILES] = run;
    }
    __syncthreads();
    const int m = min(nloc, MAXF);
    for (int j = tid; j < m; j += 256) {
        const int p = list[j];
        const int key = (p >> 9) >> 4;
        const int pos = atomicAdd(&cur[key], 1);
        sorted[n * MAXF + off_s[key] + pos] = p;
    }
    if (tid <= NTILES) offs_g[n * 32 + tid] = n * MAXF + off_s[tid];
    if (n == 0 && tid < KLEN) kk_g[tid] = kk_s[tid];
    if (tid == 0) out[n] = 0.f;
}

// ---------------- main: register-accumulator Gaussian splat, fused min-sum ----
// Thread t owns adjacent columns 2t,2t+1; rows packed in float2 pairs so the
// splat inner loop is 8x ds_read_b64 + 16 packed FMAs (v_pk_fma_f32).
__global__ __launch_bounds__(256) void k_main(
    const float* __restrict__ sal, const int* __restrict__ offs,
    const int* __restrict__ sorted, const float* __restrict__ ssum,
    const float* __restrict__ partial, const float* __restrict__ kk_g,
    float* __restrict__ out)
{
    __shared__ v2f   kpE[84];    // row-weight pairs starting at even kpy index
    __shared__ v2f   kpO[84];    // pairs starting at odd kpy index
    __shared__ float kkx[128];   // x-kernel: [0..120] = kk, [121..127] = 0
    __shared__ int   fix_s[256];
    __shared__ float part[4];
    __shared__ float redp[4];

    const int n   = blockIdx.y;
    const int t   = blockIdx.x;
    const int r0  = t * TH;
    const int tid = threadIdx.x;

    // kpy[u] = (16 <= u <= 136) ? kk[u-16] : 0
    if (tid < 84) {
        const int u = 2 * tid;
        const float e0 = ((unsigned)(u - 16) <= 120u) ? kk_g[u - 16] : 0.f;
        const float e1 = ((unsigned)(u - 15) <= 120u) ? kk_g[u - 15] : 0.f;
        const float e2 = ((unsigned)(u - 14) <= 120u) ? kk_g[u - 14] : 0.f;
        kpE[tid] = (v2f){e0, e1};
        kpO[tid] = (v2f){e1, e2};
    }
    if (tid < 128) kkx[tid] = (tid < KLEN) ? kk_g[tid] : 0.f;
    float psal = (tid < SALB) ? partial[tid] : 0.f;   // issue early

    v2f a0[8], a1[8];
    #pragma unroll
    for (int i = 0; i < 8; ++i) { a0[i] = 0.f; a1[i] = 0.f; }

    const int b0 = max(0, t - 4);
    const int b1 = min(NTILES - 1, t + 4);
    const int s0 = offs[n * 32 + b0], s1 = offs[n * 32 + b1 + 1];

    const int c0  = 2 * tid;
    const int wlo = (tid >> 6) << 7;      // wave's column strip [wlo, wlo+127]
    const int whi = wlo + 127;

    for (int fb = s0; fb < s1; fb += 256) {
        const int m = min(256, s1 - fb);
        if (fb != s0) __syncthreads();            // protect fix_s overwrite
        if (tid < m) fix_s[tid] = sorted[fb + tid];
        __syncthreads();                          // also covers kpE/kpO/kkx once
        for (int f = 0; f < m; ++f) {
            const int p = fix_s[f];               // broadcast LDS read
            const int y = p >> 9, x = p & 511;
            const int base = r0 - y + 76;         // row-weight base in kpy
            if ((unsigned)(base - 1) >= 136u) continue;   // uniform: y skip
            if (x + RR < wlo || x - RR > whi) continue;   // wave-uniform: x skip
            const int idx0 = c0 - x + RR;
            const float wx0 = kkx[min((unsigned)idx0, 127u)];
            const float wx1 = kkx[min((unsigned)(idx0 + 1), 127u)];
            const v2f* kp = (base & 1) ? kpO : kpE;
            const int kb = base >> 1;
            #pragma unroll
            for (int i = 0; i < 8; ++i) {
                const v2f wy = kp[kb + i];        // rows 2i,2i+1 (b64 broadcast)
                a0[i] += wy * wx0;                // v_pk_fma_f32
                a1[i] += wy * wx1;
            }
        }
    }

    // reduce saliency partials -> invSal
    for (int o = 32; o > 0; o >>= 1) psal += __shfl_down(psal, o, 64);
    if ((tid & 63) == 0) redp[tid >> 6] = psal;
    __syncthreads();
    const float invSal = 1.0f / (redp[0] + redp[1] + redp[2] + redp[3]);

    const float sN    = ssum[n];
    const float invSn = sN > 0.f ? 1.0f / sN : 0.f;
    float acc = 0.f;
    #pragma unroll
    for (int i = 0; i < 8; ++i) {
        const float2 vA = ((const float2*)(sal + (size_t)(r0 + 2 * i) * WW))[tid];
        const float2 vB = ((const float2*)(sal + (size_t)(r0 + 2 * i + 1) * WW))[tid];
        acc += fminf(a0[i].x * invSn, vA.x * invSal);
        acc += fminf(a1[i].x * invSn, vA.y * invSal);
        acc += fminf(a0[i].y * invSn, vB.x * invSal);
        acc += fminf(a1[i].y * invSn, vB.y * invSal);
    }
    for (int o = 32; o > 0; o >>= 1) acc += __shfl_down(acc, o, 64);
    if ((tid & 63) == 0) part[tid >> 6] = acc;
    __syncthreads();
    if (tid == 0) atomicAdd(&out[n], part[0] + part[1] + part[2] + part[3]);
}

extern "C" void kernel_launch(void* const* d_in, const int* in_sizes, int n_in,
                              void* d_out, int out_size, void* d_ws, size_t ws_size,
                              hipStream_t stream) {
    const float* sal = (const float*)d_in[0];
    const int* ns = (const int*)d_in[1];
    const int* ys = (const int*)d_in[2];
    const int* xs = (const int*)d_in[3];
    const int nfix = in_sizes[1];
    const int batch = out_size;          // 128
    float* out = (float*)d_out;

    // ws layout (float-element offsets)
    float* ws      = (float*)d_ws;
    float* kk_g    = ws;                        // 128
    float* partial = ws + 128;                  // SALB floats (192)
    float* ssum_g  = ws + 320;                  // BATCH
    int*   offs_g  = (int*)(ws + 320 + BATCH);  // batch*32 ints
    int*   sorted  = offs_g + BATCH * 32;       // batch*MAXF ints

    k_prep<<<batch + SALB, 256, 0, stream>>>(sal, ns, ys, xs, kk_g, partial,
                                             ssum_g, offs_g, sorted, out,
                                             nfix, batch);
    k_main<<<dim3(NTILES, batch), 256, 0, stream>>>(sal, offs_g, sorted,
                                                    ssum_g, partial, kk_g, out);
}